// Round 1
// baseline (1287.344 us; speedup 1.0000x reference)
//
#include <hip/hip_runtime.h>
#include <hip/hip_bf16.h>

#define NB 2
#define NS 2048
#define NDM 1024
#define NH 16
#define ND 64
#define NM (NB * NS)   // 4096 rows total

typedef __attribute__((ext_vector_type(8))) short bf16x8;   // 8 bf16 = 4 VGPRs (MFMA A/B frag)
typedef __attribute__((ext_vector_type(4))) short short4v;  // 4 bf16 LDS store
typedef __attribute__((ext_vector_type(4))) float f32x4;    // MFMA C/D frag

__device__ __forceinline__ unsigned short f2bf(float f) {
    unsigned int u = __float_as_uint(f);
    u += 0x7fffu + ((u >> 16) & 1u);   // round-to-nearest-even
    return (unsigned short)(u >> 16);
}

// ---------------------------------------------------------------------------
// C = A[M,K] * Bw[K,N] + bias[N], fp32 in/out, bf16 MFMA inside.
// 64x64 tile/block, 4 waves in 2x2, BK=32, one 16x16x32 MFMA per (m,n) per K-step.
// ---------------------------------------------------------------------------
__global__ __launch_bounds__(256)
void gemm_bf16_64(const float* __restrict__ A, const float* __restrict__ Bw,
                  const float* __restrict__ bias, float* __restrict__ C,
                  int M, int N, int K) {
    __shared__ unsigned short As[64][48];   // [row m][k], stride 96B (16B-aligned frags, ~2-way banks)
    __shared__ unsigned short Bs[64][48];   // [col n][k]  (B stored transposed)

    const int t = threadIdx.x;
    const int lane = t & 63;
    const int wave = t >> 6;
    const int wm = wave >> 1, wn = wave & 1;
    const int m0 = blockIdx.y * 64, n0 = blockIdx.x * 64;

    f32x4 acc[2][2] = {};

    const int ar = t >> 3;          // 0..31  (A stage row)
    const int ac = (t & 7) * 4;     // 0..28  (A stage col*4)
    const int br = t >> 4;          // 0..15  (B stage k-row)
    const int bc = (t & 15) * 4;    // 0..60  (B stage col*4)

    for (int k0 = 0; k0 < K; k0 += 32) {
        // stage A tile 64x32 (fp32 -> bf16)
        #pragma unroll
        for (int rr = 0; rr < 64; rr += 32) {
            const float4 v = *(const float4*)(A + (size_t)(m0 + ar + rr) * K + k0 + ac);
            short4v s;
            s.x = (short)f2bf(v.x); s.y = (short)f2bf(v.y);
            s.z = (short)f2bf(v.z); s.w = (short)f2bf(v.w);
            *(short4v*)&As[ar + rr][ac] = s;
        }
        // stage B tile 32x64 transposed -> Bs[n][k]
        #pragma unroll
        for (int rr = 0; rr < 32; rr += 16) {
            const float4 v = *(const float4*)(Bw + (size_t)(k0 + br + rr) * N + n0 + bc);
            Bs[bc + 0][br + rr] = f2bf(v.x);
            Bs[bc + 1][br + rr] = f2bf(v.y);
            Bs[bc + 2][br + rr] = f2bf(v.z);
            Bs[bc + 3][br + rr] = f2bf(v.w);
        }
        __syncthreads();

        const int lr = lane & 15;
        const int lk = (lane >> 4) * 8;
        const bf16x8 af0 = *(const bf16x8*)&As[wm * 32 +      lr][lk];
        const bf16x8 af1 = *(const bf16x8*)&As[wm * 32 + 16 + lr][lk];
        const bf16x8 bf0 = *(const bf16x8*)&Bs[wn * 32 +      lr][lk];
        const bf16x8 bf1 = *(const bf16x8*)&Bs[wn * 32 + 16 + lr][lk];
        acc[0][0] = __builtin_amdgcn_mfma_f32_16x16x32_bf16(af0, bf0, acc[0][0], 0, 0, 0);
        acc[0][1] = __builtin_amdgcn_mfma_f32_16x16x32_bf16(af0, bf1, acc[0][1], 0, 0, 0);
        acc[1][0] = __builtin_amdgcn_mfma_f32_16x16x32_bf16(af1, bf0, acc[1][0], 0, 0, 0);
        acc[1][1] = __builtin_amdgcn_mfma_f32_16x16x32_bf16(af1, bf1, acc[1][1], 0, 0, 0);
        __syncthreads();
    }

    // epilogue: D[row=(lane>>4)*4+reg][col=lane&15] per 16x16 block
    const int lr = lane & 15;
    const int lg = lane >> 4;
    #pragma unroll
    for (int m = 0; m < 2; m++) {
        #pragma unroll
        for (int n = 0; n < 2; n++) {
            const int col = n0 + wn * 32 + n * 16 + lr;
            const float bb = bias[col];
            #pragma unroll
            for (int rg = 0; rg < 4; rg++) {
                const int row = m0 + wm * 32 + m * 16 + lg * 4 + rg;
                C[(size_t)row * N + col] = acc[m][n][rg] + bb;
            }
        }
    }
}

// ---------------------------------------------------------------------------
// Causal flash attention, fp32 SIMT. qkv: [NM][3*NDM] (q|k|v concat in cols).
// One block = one (b, h, 32-row q-tile). 256 threads: 8 threads per q-row,
// each owns 4 key-columns per 32-key tile. Online softmax per row via shfl.
// O: [NM][NDM] with head-interleaved columns.
// ---------------------------------------------------------------------------
__global__ __launch_bounds__(256)
void attn_fwd(const float* __restrict__ qkv, float* __restrict__ O) {
    const int t   = threadIdx.x;
    const int blk = blockIdx.x;
    const int qt  = blk & (NS / 32 - 1);   // 0..63
    const int bh  = blk >> 6;              // 0..31
    const int h   = bh & (NH - 1);
    const int b   = bh >> 4;
    const int iq0 = qt * 32;

    __shared__ float Qs[32][68];
    __shared__ float Ks[32][68];
    __shared__ float Vs[32][68];

    const size_t rs = 3 * NDM;
    const float* qb = qkv + (size_t)b * NS * rs + h * ND;
    const float* kb = qb + NDM;
    const float* vb = qb + 2 * NDM;

    // load Q tile (32x64)
    {
        const int rr = t >> 3, q4 = (t & 7) * 4;
        const float* src = qb + (size_t)(iq0 + rr) * rs + q4;
        *(float4*)&Qs[rr][q4]      = *(const float4*)(src);
        *(float4*)&Qs[rr][q4 + 32] = *(const float4*)(src + 32);
    }

    const int r  = t >> 3;     // q row in tile
    const int c  = t & 7;      // key group
    const int qi = iq0 + r;    // global q index
    const int j0 = c * 4;

    float o[64];
    #pragma unroll
    for (int d = 0; d < 64; d++) o[d] = 0.f;
    float m = -INFINITY, l = 0.f;

    const int nkt = qt + 1;    // causal: only tiles jt*32 <= iq0
    for (int jt = 0; jt < nkt; jt++) {
        // stage K/V tile (32x64 each)
        {
            const int rr = t >> 3, q4 = (t & 7) * 4;
            const float* ks = kb + (size_t)(jt * 32 + rr) * rs + q4;
            const float* vs = vb + (size_t)(jt * 32 + rr) * rs + q4;
            *(float4*)&Ks[rr][q4]      = *(const float4*)(ks);
            *(float4*)&Ks[rr][q4 + 32] = *(const float4*)(ks + 32);
            *(float4*)&Vs[rr][q4]      = *(const float4*)(vs);
            *(float4*)&Vs[rr][q4 + 32] = *(const float4*)(vs + 32);
        }
        __syncthreads();

        // S = Q K^T for this thread's 4 keys
        float s0 = 0.f, s1 = 0.f, s2 = 0.f, s3 = 0.f;
        #pragma unroll
        for (int d4 = 0; d4 < 16; d4++) {
            const float4 q  = *(const float4*)&Qs[r][d4 * 4];
            const float4 k0 = *(const float4*)&Ks[j0 + 0][d4 * 4];
            const float4 k1 = *(const float4*)&Ks[j0 + 1][d4 * 4];
            const float4 k2 = *(const float4*)&Ks[j0 + 2][d4 * 4];
            const float4 k3 = *(const float4*)&Ks[j0 + 3][d4 * 4];
            s0 += q.x * k0.x + q.y * k0.y + q.z * k0.z + q.w * k0.w;
            s1 += q.x * k1.x + q.y * k1.y + q.z * k1.z + q.w * k1.w;
            s2 += q.x * k2.x + q.y * k2.y + q.z * k2.z + q.w * k2.w;
            s3 += q.x * k3.x + q.y * k3.y + q.z * k3.z + q.w * k3.w;
        }
        const float scl = 0.125f;   // D^-0.5
        s0 *= scl; s1 *= scl; s2 *= scl; s3 *= scl;

        // causal mask
        const int kj = jt * 32 + j0;
        if (kj + 0 > qi) s0 = -INFINITY;
        if (kj + 1 > qi) s1 = -INFINITY;
        if (kj + 2 > qi) s2 = -INFINITY;
        if (kj + 3 > qi) s3 = -INFINITY;

        // row max across this thread's 4 + the 8 threads of the row
        float pm = fmaxf(fmaxf(s0, s1), fmaxf(s2, s3));
        pm = fmaxf(pm, __shfl_xor(pm, 1));
        pm = fmaxf(pm, __shfl_xor(pm, 2));
        pm = fmaxf(pm, __shfl_xor(pm, 4));
        const float mn    = fmaxf(m, pm);
        const float alpha = __expf(m - mn);   // m=-inf first iter -> 0
        const float p0 = __expf(s0 - mn);
        const float p1 = __expf(s1 - mn);
        const float p2 = __expf(s2 - mn);
        const float p3 = __expf(s3 - mn);
        float ps = p0 + p1 + p2 + p3;
        ps += __shfl_xor(ps, 1);
        ps += __shfl_xor(ps, 2);
        ps += __shfl_xor(ps, 4);
        l = l * alpha + ps;
        m = mn;

        // O partial += P * V (this thread's 4 keys)
        #pragma unroll
        for (int d4 = 0; d4 < 16; d4++) {
            const float4 v0 = *(const float4*)&Vs[j0 + 0][d4 * 4];
            const float4 v1 = *(const float4*)&Vs[j0 + 1][d4 * 4];
            const float4 v2 = *(const float4*)&Vs[j0 + 2][d4 * 4];
            const float4 v3 = *(const float4*)&Vs[j0 + 3][d4 * 4];
            float* op = &o[d4 * 4];
            op[0] = op[0] * alpha + p0 * v0.x + p1 * v1.x + p2 * v2.x + p3 * v3.x;
            op[1] = op[1] * alpha + p0 * v0.y + p1 * v1.y + p2 * v2.y + p3 * v3.y;
            op[2] = op[2] * alpha + p0 * v0.z + p1 * v1.z + p2 * v2.z + p3 * v3.z;
            op[3] = op[3] * alpha + p0 * v0.w + p1 * v1.w + p2 * v2.w + p3 * v3.w;
        }
        __syncthreads();
    }

    // combine partial O across the 8 threads of the row (butterfly)
    #pragma unroll
    for (int d = 0; d < 64; d++) {
        o[d] += __shfl_xor(o[d], 1);
        o[d] += __shfl_xor(o[d], 2);
        o[d] += __shfl_xor(o[d], 4);
    }
    const float inv = 1.f / l;
    if (c == 0) {
        float* dst = O + (size_t)(b * NS + qi) * NDM + h * ND;
        #pragma unroll
        for (int d = 0; d < 64; d++) dst[d] = o[d] * inv;
    }
}

// ---------------------------------------------------------------------------
extern "C" void kernel_launch(void* const* d_in, const int* in_sizes, int n_in,
                              void* d_out, int out_size, void* d_ws, size_t ws_size,
                              hipStream_t stream) {
    const float* x     = (const float*)d_in[0];
    const float* w_qkv = (const float*)d_in[1];
    const float* b_qkv = (const float*)d_in[2];
    const float* w_out = (const float*)d_in[3];
    const float* b_out = (const float*)d_in[4];
    float* out = (float*)d_out;

    float* qkv  = (float*)d_ws;                       // [4096][3072] fp32 = 50.3 MB
    float* atto = qkv + (size_t)NM * 3 * NDM;         // [4096][1024] fp32 = 16.8 MB

    // 1) QKV projection: [4096,1024] @ [1024,3072] + b_qkv
    gemm_bf16_64<<<dim3(3 * NDM / 64, NM / 64), dim3(256), 0, stream>>>(
        x, w_qkv, b_qkv, qkv, NM, 3 * NDM, NDM);

    // 2) causal attention per (b,h,q-tile)
    attn_fwd<<<dim3(NB * NH * (NS / 32)), dim3(256), 0, stream>>>(qkv, atto);

    // 3) output projection: [4096,1024] @ [1024,1024] + b_out
    gemm_bf16_64<<<dim3(NDM / 64, NM / 64), dim3(256), 0, stream>>>(
        atto, w_out, b_out, out, NM, NDM, NDM);
}

// Round 2
// 292.977 us; speedup vs baseline: 4.3940x; 4.3940x over previous
//
#include <hip/hip_runtime.h>
#include <hip/hip_bf16.h>

#define NB 2
#define NS 2048
#define NDM 1024
#define NH 16
#define ND 64
#define NM (NB * NS)   // 4096
#define SCALE 0.125f   // D^-0.5

typedef __attribute__((ext_vector_type(8))) short bf16x8;   // MFMA A/B frag (4 VGPRs)
typedef __attribute__((ext_vector_type(4))) float f32x4;    // MFMA C/D frag

__device__ __forceinline__ unsigned short f2bf(float f) {
    unsigned int u = __float_as_uint(f);
    u += 0x7fffu + ((u >> 16) & 1u);   // RNE
    return (unsigned short)(u >> 16);
}

// Swizzled short-index into a [rows][64] bf16 LDS tile. 8-element groups are
// XOR'd by (row ^ row>>2)&7 so that b128 fragment reads (16 lanes, same col
// group, rows 0..15) and staging writes land <=2-way per bank (free).
__device__ __forceinline__ int swz(int row, int col) {
    const int sw = (row ^ (row >> 2)) & 7;
    return row * 64 + ((((col >> 3) ^ sw) & 7) << 3) + (col & 7);
}

// ---------------------------------------------------------------------------
// fp32 -> bf16 elementwise (x)
// ---------------------------------------------------------------------------
__global__ __launch_bounds__(256)
void convert_bf16(const float* __restrict__ in, unsigned short* __restrict__ out, int n8) {
    int i = blockIdx.x * 256 + threadIdx.x;
    const int stride = gridDim.x * 256;
    for (; i < n8; i += stride) {
        const float4 a = ((const float4*)in)[i * 2];
        const float4 b = ((const float4*)in)[i * 2 + 1];
        bf16x8 v;
        v[0] = (short)f2bf(a.x); v[1] = (short)f2bf(a.y);
        v[2] = (short)f2bf(a.z); v[3] = (short)f2bf(a.w);
        v[4] = (short)f2bf(b.x); v[5] = (short)f2bf(b.y);
        v[6] = (short)f2bf(b.z); v[7] = (short)f2bf(b.w);
        *(bf16x8*)(out + (size_t)i * 8) = v;
    }
}

// ---------------------------------------------------------------------------
// W[K][N] fp32 -> WT[N][K] bf16, 64x64 LDS-tiled transpose
// ---------------------------------------------------------------------------
__global__ __launch_bounds__(256)
void transpose_bf16(const float* __restrict__ W, unsigned short* __restrict__ WT,
                    int K, int N) {
    __shared__ float Ts[64][65];
    const int n0 = blockIdx.x * 64, k0 = blockIdx.y * 64;
    const int t = threadIdx.x;
    {
        const int c4 = (t & 15) * 4;
        #pragma unroll
        for (int p = 0; p < 4; p++) {
            const int r = (t >> 4) + p * 16;
            const float4 v = *(const float4*)(W + (size_t)(k0 + r) * N + n0 + c4);
            Ts[r][c4] = v.x; Ts[r][c4 + 1] = v.y; Ts[r][c4 + 2] = v.z; Ts[r][c4 + 3] = v.w;
        }
    }
    __syncthreads();
    {
        const int cc8 = (t & 7) * 8;
        #pragma unroll
        for (int p = 0; p < 2; p++) {
            const int rr = (t >> 3) + p * 32;
            bf16x8 v;
            #pragma unroll
            for (int j = 0; j < 8; j++) v[j] = (short)f2bf(Ts[cc8 + j][rr]);
            *(bf16x8*)(WT + (size_t)(n0 + rr) * K + k0 + cc8) = v;
        }
    }
}

// ---------------------------------------------------------------------------
// C = A[M,K] * BT[N,K]^T + bias. bf16 in, fp32 accumulate, out fp32 or bf16.
// 64x64 tile, 4 waves 2x2, BK=64 (2 MFMA k-halves), vectorized staging.
// ---------------------------------------------------------------------------
template<int OUT_BF16>
__global__ __launch_bounds__(256)
void gemm64(const unsigned short* __restrict__ A, const unsigned short* __restrict__ BT,
            const float* __restrict__ bias, void* __restrict__ Cv,
            int M, int N, int K) {
    __shared__ unsigned short As[64][72];   // stride 144B -> b128 frag reads 2-way (free)
    __shared__ unsigned short Bs[64][72];

    const int t = threadIdx.x, lane = t & 63, wave = t >> 6;
    const int wm = wave >> 1, wn = wave & 1;
    const int m0 = blockIdx.y * 64, n0 = blockIdx.x * 64;

    f32x4 acc[2][2];
    #pragma unroll
    for (int m = 0; m < 2; m++)
        #pragma unroll
        for (int n = 0; n < 2; n++)
            #pragma unroll
            for (int r = 0; r < 4; r++) acc[m][n][r] = 0.f;

    const int sr = t >> 3, sc = (t & 7) * 8;
    const int fr = lane & 15, fk = (lane >> 4) * 8;

    for (int k0 = 0; k0 < K; k0 += 64) {
        #pragma unroll
        for (int p = 0; p < 2; p++) {
            *(bf16x8*)&As[sr + p * 32][sc] =
                *(const bf16x8*)(A + (size_t)(m0 + sr + p * 32) * K + k0 + sc);
            *(bf16x8*)&Bs[sr + p * 32][sc] =
                *(const bf16x8*)(BT + (size_t)(n0 + sr + p * 32) * K + k0 + sc);
        }
        __syncthreads();

        bf16x8 af[2][2], bfr[2][2];
        #pragma unroll
        for (int m = 0; m < 2; m++)
            #pragma unroll
            for (int kk = 0; kk < 2; kk++)
                af[m][kk] = *(const bf16x8*)&As[wm * 32 + m * 16 + fr][kk * 32 + fk];
        #pragma unroll
        for (int n = 0; n < 2; n++)
            #pragma unroll
            for (int kk = 0; kk < 2; kk++)
                bfr[n][kk] = *(const bf16x8*)&Bs[wn * 32 + n * 16 + fr][kk * 32 + fk];
        #pragma unroll
        for (int m = 0; m < 2; m++)
            #pragma unroll
            for (int n = 0; n < 2; n++)
                #pragma unroll
                for (int kk = 0; kk < 2; kk++)
                    acc[m][n] = __builtin_amdgcn_mfma_f32_16x16x32_bf16(
                        af[m][kk], bfr[n][kk], acc[m][n], 0, 0, 0);
        __syncthreads();
    }

    const int lg = lane >> 4;
    #pragma unroll
    for (int m = 0; m < 2; m++)
        #pragma unroll
        for (int n = 0; n < 2; n++) {
            const int col = n0 + wn * 32 + n * 16 + fr;
            const float bb = bias[col];
            #pragma unroll
            for (int rg = 0; rg < 4; rg++) {
                const int row = m0 + wm * 32 + m * 16 + lg * 4 + rg;
                const float v = acc[m][n][rg] + bb;
                if (OUT_BF16) ((unsigned short*)Cv)[(size_t)row * N + col] = f2bf(v);
                else          ((float*)Cv)[(size_t)row * N + col] = v;
            }
        }
}

// ---------------------------------------------------------------------------
// Causal MFMA flash attention. qkv bf16 [NM][3*NDM], O bf16 [NM][NDM].
// Block = (qt, h, b): 64 q rows, 4 waves x 16 rows. KV tiles of 64 keys.
// K LDS row=key col=d (swz); V LDS TRANSPOSED row=d col=key (swz);
// P per-wave [16][64] (swz). All MFMA frag reads are b128, <=2-way banks.
// ---------------------------------------------------------------------------
__global__ __launch_bounds__(256)
void attn_mfma(const unsigned short* __restrict__ qkv, unsigned short* __restrict__ O) {
    const int qt = blockIdx.x;           // 0..31
    const int h  = blockIdx.y;           // 0..15
    const int b  = blockIdx.z;           // 0..1
    const int q0 = qt * 64;
    const int t = threadIdx.x, lane = t & 63, w = t >> 6;

    __shared__ unsigned short Kt[64 * 64];      // 8 KB (holds Q during prologue)
    __shared__ unsigned short Vt[64 * 64];      // 8 KB, transposed
    __shared__ unsigned short Ps[4][16 * 64];   // 8 KB, per-wave

    const size_t rs = 3 * NDM;
    const unsigned short* qb = qkv + (size_t)b * NS * rs + h * ND;
    const unsigned short* kbp = qb + NDM;
    const unsigned short* vbp = qb + 2 * NDM;

    const int sr = t >> 3, sc = (t & 7) * 8;    // staging: row, col8
    const int fr = lane & 15, fk = (lane >> 4) * 8;

    // ---- stage Q (64 rows) into Kt, pull per-wave A-fragments to registers
    #pragma unroll
    for (int p = 0; p < 2; p++) {
        const bf16x8 v = *(const bf16x8*)(qb + (size_t)(q0 + sr + p * 32) * rs + sc);
        *(bf16x8*)&Kt[swz(sr + p * 32, sc)] = v;
    }
    __syncthreads();
    bf16x8 qf[2];
    qf[0] = *(const bf16x8*)&Kt[swz(w * 16 + fr, fk)];
    qf[1] = *(const bf16x8*)&Kt[swz(w * 16 + fr, 32 + fk)];

    f32x4 oacc[4];
    #pragma unroll
    for (int d = 0; d < 4; d++)
        #pragma unroll
        for (int r = 0; r < 4; r++) oacc[d][r] = 0.f;
    float mrow[4] = {-INFINITY, -INFINITY, -INFINITY, -INFINITY};
    float lrow[4] = {0.f, 0.f, 0.f, 0.f};

    for (int jt = 0; jt <= qt; jt++) {
        __syncthreads();   // prior reads of Kt/Vt (or Q frags) complete
        // ---- stage K tile + V tile (transposed)
        #pragma unroll
        for (int p = 0; p < 2; p++) {
            const int key = jt * 64 + sr + p * 32;
            const bf16x8 kv = *(const bf16x8*)(kbp + (size_t)key * rs + sc);
            *(bf16x8*)&Kt[swz(sr + p * 32, sc)] = kv;
            const bf16x8 vv = *(const bf16x8*)(vbp + (size_t)key * rs + sc);
            #pragma unroll
            for (int j = 0; j < 8; j++)
                Vt[swz(sc + j, sr + p * 32)] = (unsigned short)vv[j];
        }
        __syncthreads();

        // ---- S = Q K^T  (16 q rows x 64 keys per wave)
        f32x4 sacc[4];
        #pragma unroll
        for (int kbi = 0; kbi < 4; kbi++) {
            #pragma unroll
            for (int r = 0; r < 4; r++) sacc[kbi][r] = 0.f;
            const bf16x8 kf0 = *(const bf16x8*)&Kt[swz(kbi * 16 + fr, fk)];
            const bf16x8 kf1 = *(const bf16x8*)&Kt[swz(kbi * 16 + fr, 32 + fk)];
            sacc[kbi] = __builtin_amdgcn_mfma_f32_16x16x32_bf16(qf[0], kf0, sacc[kbi], 0, 0, 0);
            sacc[kbi] = __builtin_amdgcn_mfma_f32_16x16x32_bf16(qf[1], kf1, sacc[kbi], 0, 0, 0);
        }
        #pragma unroll
        for (int kbi = 0; kbi < 4; kbi++)
            #pragma unroll
            for (int reg = 0; reg < 4; reg++) sacc[kbi][reg] *= SCALE;

        if (jt == qt) {   // causal mask, diagonal tile only
            #pragma unroll
            for (int kbi = 0; kbi < 4; kbi++) {
                const int keyg = jt * 64 + kbi * 16 + fr;
                #pragma unroll
                for (int reg = 0; reg < 4; reg++) {
                    const int qg = q0 + w * 16 + (lane >> 4) * 4 + reg;
                    if (keyg > qg) sacc[kbi][reg] = -INFINITY;
                }
            }
        }

        // ---- online softmax per q-row (row spread over 16 lanes, 4 rows/lane)
        float alpha[4], p[4][4];
        #pragma unroll
        for (int reg = 0; reg < 4; reg++) {
            float pm = fmaxf(fmaxf(sacc[0][reg], sacc[1][reg]),
                             fmaxf(sacc[2][reg], sacc[3][reg]));
            pm = fmaxf(pm, __shfl_xor(pm, 1));
            pm = fmaxf(pm, __shfl_xor(pm, 2));
            pm = fmaxf(pm, __shfl_xor(pm, 4));
            pm = fmaxf(pm, __shfl_xor(pm, 8));
            const float mn = fmaxf(mrow[reg], pm);
            alpha[reg] = __expf(mrow[reg] - mn);
            mrow[reg] = mn;
            float ps = 0.f;
            #pragma unroll
            for (int kbi = 0; kbi < 4; kbi++) {
                p[kbi][reg] = __expf(sacc[kbi][reg] - mn);
                ps += p[kbi][reg];
            }
            ps += __shfl_xor(ps, 1);
            ps += __shfl_xor(ps, 2);
            ps += __shfl_xor(ps, 4);
            ps += __shfl_xor(ps, 8);
            lrow[reg] = lrow[reg] * alpha[reg] + ps;
        }

        // ---- P -> bf16 -> per-wave LDS (swz), rescale O
        const int prow = (lane >> 4) * 4;
        #pragma unroll
        for (int kbi = 0; kbi < 4; kbi++)
            #pragma unroll
            for (int reg = 0; reg < 4; reg++)
                Ps[w][swz(prow + reg, kbi * 16 + fr)] = f2bf(p[kbi][reg]);
        #pragma unroll
        for (int dblk = 0; dblk < 4; dblk++)
            #pragma unroll
            for (int reg = 0; reg < 4; reg++) oacc[dblk][reg] *= alpha[reg];
        __syncthreads();   // P visible (and all waves past Kt/Vt... next overwrite gated at loop top)

        // ---- O += P V
        const bf16x8 pf0 = *(const bf16x8*)&Ps[w][swz(fr, fk)];
        const bf16x8 pf1 = *(const bf16x8*)&Ps[w][swz(fr, 32 + fk)];
        #pragma unroll
        for (int dblk = 0; dblk < 4; dblk++) {
            const bf16x8 vf0 = *(const bf16x8*)&Vt[swz(dblk * 16 + fr, fk)];
            const bf16x8 vf1 = *(const bf16x8*)&Vt[swz(dblk * 16 + fr, 32 + fk)];
            oacc[dblk] = __builtin_amdgcn_mfma_f32_16x16x32_bf16(pf0, vf0, oacc[dblk], 0, 0, 0);
            oacc[dblk] = __builtin_amdgcn_mfma_f32_16x16x32_bf16(pf1, vf1, oacc[dblk], 0, 0, 0);
        }
    }

    // ---- epilogue: O / l, bf16 out (head-interleaved cols)
    #pragma unroll
    for (int reg = 0; reg < 4; reg++) {
        const float inv = 1.f / lrow[reg];
        const int row = q0 + w * 16 + (lane >> 4) * 4 + reg;
        unsigned short* dst = O + (size_t)(b * NS + row) * NDM + h * ND;
        #pragma unroll
        for (int dblk = 0; dblk < 4; dblk++)
            dst[dblk * 16 + fr] = f2bf(oacc[dblk][reg] * inv);
    }
}

// ---------------------------------------------------------------------------
extern "C" void kernel_launch(void* const* d_in, const int* in_sizes, int n_in,
                              void* d_out, int out_size, void* d_ws, size_t ws_size,
                              hipStream_t stream) {
    const float* x     = (const float*)d_in[0];
    const float* w_qkv = (const float*)d_in[1];
    const float* b_qkv = (const float*)d_in[2];
    const float* w_out = (const float*)d_in[3];
    const float* b_out = (const float*)d_in[4];
    float* out = (float*)d_out;

    unsigned short* xb   = (unsigned short*)d_ws;                    //  8 MB [4096][1024]
    unsigned short* wqT  = xb  + (size_t)NM * NDM;                   //  6 MB [3072][1024]
    unsigned short* woT  = wqT + (size_t)3 * NDM * NDM;              //  2 MB [1024][1024]
    unsigned short* qkv  = woT + (size_t)NDM * NDM;                  // 24 MB [4096][3072]
    unsigned short* atto = qkv + (size_t)NM * 3 * NDM;               //  8 MB [4096][1024]

    // 0) convert/transpose inputs to bf16
    convert_bf16<<<2048, 256, 0, stream>>>(x, xb, NM * NDM / 8);
    transpose_bf16<<<dim3(3 * NDM / 64, NDM / 64), 256, 0, stream>>>(w_qkv, wqT, NDM, 3 * NDM);
    transpose_bf16<<<dim3(NDM / 64, NDM / 64), 256, 0, stream>>>(w_out, woT, NDM, NDM);

    // 1) qkv = x @ w_qkv + b  (bf16 out)
    gemm64<1><<<dim3(3 * NDM / 64, NM / 64), 256, 0, stream>>>(
        xb, wqT, b_qkv, qkv, NM, 3 * NDM, NDM);

    // 2) causal MFMA attention (bf16 out)
    attn_mfma<<<dim3(NS / 64, NH, NB), 256, 0, stream>>>(qkv, atto);

    // 3) out = atto @ w_out + b  (fp32 out)
    gemm64<0><<<dim3(NDM / 64, NM / 64), 256, 0, stream>>>(
        atto, woT, b_out, out, NM, NDM, NDM);
}

// Round 3
// 214.195 us; speedup vs baseline: 6.0102x; 1.3678x over previous
//
#include <hip/hip_runtime.h>
#include <hip/hip_bf16.h>

#define NB 2
#define NS 2048
#define NDM 1024
#define NH 16
#define ND 64
#define NM (NB * NS)   // 4096
#define SCALE 0.125f   // D^-0.5

typedef __attribute__((ext_vector_type(8))) short bf16x8;   // MFMA A/B frag (4 VGPRs)
typedef __attribute__((ext_vector_type(4))) float f32x4;    // MFMA C/D frag

__device__ __forceinline__ unsigned short f2bf(float f) {
    unsigned int u = __float_as_uint(f);
    u += 0x7fffu + ((u >> 16) & 1u);   // RNE
    return (unsigned short)(u >> 16);
}

// async global->LDS, 16B per lane. LDS dest = wave-uniform base + lane*16.
__device__ __forceinline__ void gload16(const unsigned short* g, unsigned short* l) {
    __builtin_amdgcn_global_load_lds(
        (const __attribute__((address_space(1))) void*)g,
        (__attribute__((address_space(3))) void*)l, 16, 0, 0);
}

// ---------------------------------------------------------------------------
// fp32 -> bf16 elementwise
// ---------------------------------------------------------------------------
__global__ __launch_bounds__(256)
void convert_bf16(const float* __restrict__ in, unsigned short* __restrict__ out, int n8) {
    int i = blockIdx.x * 256 + threadIdx.x;
    const int stride = gridDim.x * 256;
    for (; i < n8; i += stride) {
        const float4 a = ((const float4*)in)[i * 2];
        const float4 b = ((const float4*)in)[i * 2 + 1];
        bf16x8 v;
        v[0] = (short)f2bf(a.x); v[1] = (short)f2bf(a.y);
        v[2] = (short)f2bf(a.z); v[3] = (short)f2bf(a.w);
        v[4] = (short)f2bf(b.x); v[5] = (short)f2bf(b.y);
        v[6] = (short)f2bf(b.z); v[7] = (short)f2bf(b.w);
        *(bf16x8*)(out + (size_t)i * 8) = v;
    }
}

// ---------------------------------------------------------------------------
// W[K][N] fp32 -> WT[N][K] bf16 (64x64 LDS-tiled)
// ---------------------------------------------------------------------------
__global__ __launch_bounds__(256)
void transpose_bf16(const float* __restrict__ W, unsigned short* __restrict__ WT,
                    int K, int N) {
    __shared__ float Ts[64][65];
    const int n0 = blockIdx.x * 64, k0 = blockIdx.y * 64;
    const int t = threadIdx.x;
    {
        const int c4 = (t & 15) * 4;
        #pragma unroll
        for (int p = 0; p < 4; p++) {
            const int r = (t >> 4) + p * 16;
            const float4 v = *(const float4*)(W + (size_t)(k0 + r) * N + n0 + c4);
            Ts[r][c4] = v.x; Ts[r][c4 + 1] = v.y; Ts[r][c4 + 2] = v.z; Ts[r][c4 + 3] = v.w;
        }
    }
    __syncthreads();
    {
        const int cc8 = (t & 7) * 8;
        #pragma unroll
        for (int p = 0; p < 2; p++) {
            const int rr = (t >> 3) + p * 32;
            bf16x8 v;
            #pragma unroll
            for (int j = 0; j < 8; j++) v[j] = (short)f2bf(Ts[cc8 + j][rr]);
            *(bf16x8*)(WT + (size_t)(n0 + rr) * K + k0 + cc8) = v;
        }
    }
}

// ---------------------------------------------------------------------------
// m97-style 128x128 GEMM, BK=32, global_load_lds(16B) with swizzled source.
// A[M,K] bf16, BT[N,K] bf16. MODE 0: fp32 C row-major + bias.
// MODE 1: split-QKV epilogue -> qH/kH [bh][s][d], vT [bh][d][s] (bf16) + bias.
// LDS tile [128][32]: 8-short group g of row r holds global group g ^ sw4(r),
// sw4(r) = (r ^ r>>2) & 3  -> b128 frag reads are 2-way (free).
// ---------------------------------------------------------------------------
template<int MODE>
__global__ __launch_bounds__(256)
void gemm128(const unsigned short* __restrict__ A, const unsigned short* __restrict__ BT,
             const float* __restrict__ bias, void* __restrict__ Cv,
             unsigned short* __restrict__ qH, unsigned short* __restrict__ kH,
             unsigned short* __restrict__ vT,
             int M, int N, int K) {
    __shared__ unsigned short As[128 * 32];   // 8 KB
    __shared__ unsigned short Bs[128 * 32];   // 8 KB

    const int t = threadIdx.x, lane = t & 63, wv = t >> 6;
    const int wm = wv >> 1, wn = wv & 1;
    const int m0 = blockIdx.y * 128, n0 = blockIdx.x * 128;
    const int fr = lane & 15, fg = lane >> 4;   // frag row, k-group 0..3

    f32x4 acc[4][4];
    #pragma unroll
    for (int m = 0; m < 4; m++)
        #pragma unroll
        for (int n = 0; n < 4; n++)
            #pragma unroll
            for (int r = 0; r < 4; r++) acc[m][n][r] = 0.f;

    for (int k0 = 0; k0 < K; k0 += 32) {
        __syncthreads();   // prior frag reads done before overwrite
        #pragma unroll
        for (int i = 0; i < 2; i++) {
            const int u = t + i * 256;            // 16B unit: row = u>>2, grp = u&3
            const int row = u >> 2;
            const int grp = (u & 3) ^ ((row ^ (row >> 2)) & 3);
            unsigned short* ldsA = &As[(i * 256 + wv * 64) * 8];
            unsigned short* ldsB = &Bs[(i * 256 + wv * 64) * 8];
            gload16(A  + (size_t)(m0 + row) * K + k0 + grp * 8, ldsA);
            gload16(BT + (size_t)(n0 + row) * K + k0 + grp * 8, ldsB);
        }
        __syncthreads();   // vmcnt(0) drain + barrier: tiles visible

        bf16x8 af[4], bfv[4];
        #pragma unroll
        for (int m = 0; m < 4; m++) {
            const int row = wm * 64 + m * 16 + fr;
            const int g = fg ^ ((row ^ (row >> 2)) & 3);
            af[m] = *(const bf16x8*)&As[row * 32 + g * 8];
        }
        #pragma unroll
        for (int n = 0; n < 4; n++) {
            const int row = wn * 64 + n * 16 + fr;
            const int g = fg ^ ((row ^ (row >> 2)) & 3);
            bfv[n] = *(const bf16x8*)&Bs[row * 32 + g * 8];
        }
        #pragma unroll
        for (int m = 0; m < 4; m++)
            #pragma unroll
            for (int n = 0; n < 4; n++)
                acc[m][n] = __builtin_amdgcn_mfma_f32_16x16x32_bf16(
                    af[m], bfv[n], acc[m][n], 0, 0, 0);
    }

    const int lg = lane >> 4;
    #pragma unroll
    for (int m = 0; m < 4; m++)
        #pragma unroll
        for (int n = 0; n < 4; n++) {
            const int col = n0 + wn * 64 + n * 16 + fr;
            const float bb = bias[col];
            #pragma unroll
            for (int rg = 0; rg < 4; rg++) {
                const int row = m0 + wm * 64 + m * 16 + lg * 4 + rg;
                const float v = acc[m][n][rg] + bb;
                if (MODE == 0) {
                    ((float*)Cv)[(size_t)row * N + col] = v;
                } else {
                    const int part = col >> 10;          // 0=q 1=k 2=v
                    const int h = (col >> 6) & 15, d = col & 63;
                    const int bb2 = row >> 11, s = row & (NS - 1);
                    const size_t bh = (size_t)bb2 * NH + h;
                    const unsigned short bf = f2bf(v);
                    if (part == 0)      qH[(bh * NS + s) * ND + d] = bf;
                    else if (part == 1) kH[(bh * NS + s) * ND + d] = bf;
                    else                vT[(bh * ND + d) * NS + s] = bf;
                }
            }
        }
}

// ---------------------------------------------------------------------------
// Causal MFMA flash attention. qH/kH [bh][s][d], vT [bh][d][s], all bf16.
// Block = 64 q rows (4 waves x 16), KVBLK = 128. LPT order (qt descending).
// K LDS [128key][64d], V LDS [64d][128key], both via global_load_lds with
// swizzled source (grp ^= row&7). P per-wave private [16][128] (no barrier
// between softmax and PV; ds ops are in-order within a wave).
// 2 barriers per KV tile. atto out: [token][h*64+d] bf16.
// ---------------------------------------------------------------------------
__global__ __launch_bounds__(256)
void attn_mfma(const unsigned short* __restrict__ qH, const unsigned short* __restrict__ kH,
               const unsigned short* __restrict__ vT, unsigned short* __restrict__ atto) {
    const int bx = blockIdx.x;
    const int qt = (NS / 64 - 1) - (bx >> 5);   // 31..0 : longest blocks first (LPT)
    const int bh = bx & 31;
    const int h = bh & (NH - 1), b = bh >> 4;
    const int q0 = qt * 64;
    const int t = threadIdx.x, lane = t & 63, wv = t >> 6;
    const int fr = lane & 15, fg = lane >> 4;
    const int fk = fg * 8;

    __shared__ unsigned short Kt[128 * 64];     // 16 KB
    __shared__ unsigned short Vt[64 * 128];     // 16 KB
    __shared__ unsigned short Ps[4][16 * 128];  // 16 KB, wave-private quarters

    const unsigned short* kb = kH + (size_t)bh * NS * ND;
    const unsigned short* vb = vT + (size_t)bh * ND * NS;

    // Q fragments straight from global (A-frag: row=fr q-row, k = kk*32+fk)
    bf16x8 qf[2];
    {
        const unsigned short* qrow = qH + ((size_t)bh * NS + q0 + wv * 16 + fr) * ND;
        qf[0] = *(const bf16x8*)(qrow + fk);
        qf[1] = *(const bf16x8*)(qrow + 32 + fk);
    }

    f32x4 oacc[4];
    #pragma unroll
    for (int d = 0; d < 4; d++)
        #pragma unroll
        for (int r = 0; r < 4; r++) oacc[d][r] = 0.f;
    float mrow[4] = {-INFINITY, -INFINITY, -INFINITY, -INFINITY};
    float lrow[4] = {0.f, 0.f, 0.f, 0.f};

    const int ntiles = (qt >> 1) + 1;
    for (int jt = 0; jt < ntiles; jt++) {
        __syncthreads();   // all waves done reading Kt/Vt from prior tile
        // stage K: 1024 units; row = u>>3 (8 grps of 8 shorts), grp ^= row&7
        #pragma unroll
        for (int i = 0; i < 4; i++) {
            const int u = t + i * 256;
            const int row = u >> 3;
            const int grp = (u & 7) ^ (row & 7);
            gload16(kb + (size_t)(jt * 128 + row) * ND + grp * 8,
                    &Kt[(i * 256 + wv * 64) * 8]);
        }
        // stage V^T: row = d = u>>4 (16 grps), grp ^= row&7
        #pragma unroll
        for (int i = 0; i < 4; i++) {
            const int u = t + i * 256;
            const int row = u >> 4;
            const int grp = (u & 15) ^ (row & 7);
            gload16(vb + (size_t)row * NS + jt * 128 + grp * 8,
                    &Vt[(i * 256 + wv * 64) * 8]);
        }
        __syncthreads();   // staged tiles visible

        // ---- S = Q K^T : 8 key-blocks x 2 k-halves
        f32x4 sacc[8];
        #pragma unroll
        for (int kbi = 0; kbi < 8; kbi++) {
            #pragma unroll
            for (int r = 0; r < 4; r++) sacc[kbi][r] = 0.f;
            const int row = kbi * 16 + fr;
            const int g0 = (fg)     ^ (row & 7);
            const int g1 = (4 + fg) ^ (row & 7);
            const bf16x8 kf0 = *(const bf16x8*)&Kt[row * 64 + g0 * 8];
            const bf16x8 kf1 = *(const bf16x8*)&Kt[row * 64 + g1 * 8];
            sacc[kbi] = __builtin_amdgcn_mfma_f32_16x16x32_bf16(qf[0], kf0, sacc[kbi], 0, 0, 0);
            sacc[kbi] = __builtin_amdgcn_mfma_f32_16x16x32_bf16(qf[1], kf1, sacc[kbi], 0, 0, 0);
        }
        #pragma unroll
        for (int kbi = 0; kbi < 8; kbi++)
            #pragma unroll
            for (int r = 0; r < 4; r++) sacc[kbi][r] *= SCALE;

        if (jt == ntiles - 1) {   // only the last tile can cross the diagonal
            #pragma unroll
            for (int kbi = 0; kbi < 8; kbi++) {
                const int keyg = jt * 128 + kbi * 16 + fr;
                #pragma unroll
                for (int reg = 0; reg < 4; reg++) {
                    const int qg = q0 + wv * 16 + fg * 4 + reg;
                    if (keyg > qg) sacc[kbi][reg] = -INFINITY;
                }
            }
        }

        // ---- online softmax per q-row (row over 16 lanes, 4 rows/lane)
        float alpha[4];
        #pragma unroll
        for (int reg = 0; reg < 4; reg++) {
            float pm = sacc[0][reg];
            #pragma unroll
            for (int kbi = 1; kbi < 8; kbi++) pm = fmaxf(pm, sacc[kbi][reg]);
            pm = fmaxf(pm, __shfl_xor(pm, 1));
            pm = fmaxf(pm, __shfl_xor(pm, 2));
            pm = fmaxf(pm, __shfl_xor(pm, 4));
            pm = fmaxf(pm, __shfl_xor(pm, 8));
            const float mn = fmaxf(mrow[reg], pm);
            alpha[reg] = __expf(mrow[reg] - mn);
            mrow[reg] = mn;
            float ps = 0.f;
            #pragma unroll
            for (int kbi = 0; kbi < 8; kbi++) {
                const float p = __expf(sacc[kbi][reg] - mn);
                sacc[kbi][reg] = p;     // reuse sacc as P
                ps += p;
            }
            ps += __shfl_xor(ps, 1);
            ps += __shfl_xor(ps, 2);
            ps += __shfl_xor(ps, 4);
            ps += __shfl_xor(ps, 8);
            lrow[reg] = lrow[reg] * alpha[reg] + ps;
        }

        // ---- P -> wave-private LDS (swizzled like Vt), rescale O
        #pragma unroll
        for (int kbi = 0; kbi < 8; kbi++) {
            const int colk = kbi * 16 + fr;
            #pragma unroll
            for (int reg = 0; reg < 4; reg++) {
                const int prow = fg * 4 + reg;
                const int g = ((colk >> 3) ^ (prow & 7));
                Ps[wv][prow * 128 + g * 8 + (colk & 7)] = f2bf(sacc[kbi][reg]);
            }
        }
        #pragma unroll
        for (int dblk = 0; dblk < 4; dblk++)
            #pragma unroll
            for (int reg = 0; reg < 4; reg++) oacc[dblk][reg] *= alpha[reg];

        // ---- O += P V  (no barrier: Ps is wave-private, ds ops in-order)
        bf16x8 pf[4];
        #pragma unroll
        for (int ks = 0; ks < 4; ks++) {
            const int g = (ks * 4 + fg) ^ (fr & 7);
            pf[ks] = *(const bf16x8*)&Ps[wv][fr * 128 + g * 8];
        }
        #pragma unroll
        for (int dblk = 0; dblk < 4; dblk++) {
            const int vrow = dblk * 16 + fr;
            #pragma unroll
            for (int ks = 0; ks < 4; ks++) {
                const int g = (ks * 4 + fg) ^ (vrow & 7);
                const bf16x8 vf = *(const bf16x8*)&Vt[vrow * 128 + g * 8];
                oacc[dblk] = __builtin_amdgcn_mfma_f32_16x16x32_bf16(
                    pf[ks], vf, oacc[dblk], 0, 0, 0);
            }
        }
    }

    // ---- epilogue
    #pragma unroll
    for (int reg = 0; reg < 4; reg++) {
        const float inv = 1.f / lrow[reg];
        const int row = q0 + wv * 16 + fg * 4 + reg;
        unsigned short* dst = atto + ((size_t)b * NS + row) * NDM + h * ND;
        #pragma unroll
        for (int dblk = 0; dblk < 4; dblk++)
            dst[dblk * 16 + fr] = f2bf(oacc[dblk][reg] * inv);
    }
}

// ---------------------------------------------------------------------------
extern "C" void kernel_launch(void* const* d_in, const int* in_sizes, int n_in,
                              void* d_out, int out_size, void* d_ws, size_t ws_size,
                              hipStream_t stream) {
    const float* x     = (const float*)d_in[0];
    const float* w_qkv = (const float*)d_in[1];
    const float* b_qkv = (const float*)d_in[2];
    const float* w_out = (const float*)d_in[3];
    const float* b_out = (const float*)d_in[4];
    float* out = (float*)d_out;

    unsigned short* xb   = (unsigned short*)d_ws;             //  8 MB [4096][1024]
    unsigned short* wqT  = xb   + (size_t)NM * NDM;           //  6 MB [3072][1024]
    unsigned short* woT  = wqT  + (size_t)3 * NDM * NDM;      //  2 MB [1024][1024]
    unsigned short* qH   = woT  + (size_t)NDM * NDM;          //  8 MB [32][2048][64]
    unsigned short* kH   = qH   + (size_t)NM * NDM;           //  8 MB [32][2048][64]
    unsigned short* vT   = kH   + (size_t)NM * NDM;           //  8 MB [32][64][2048]
    unsigned short* atto = vT   + (size_t)NM * NDM;           //  8 MB [4096][1024]

    convert_bf16<<<2048, 256, 0, stream>>>(x, xb, NM * NDM / 8);
    transpose_bf16<<<dim3(3 * NDM / 64, NDM / 64), 256, 0, stream>>>(w_qkv, wqT, NDM, 3 * NDM);
    transpose_bf16<<<dim3(NDM / 64, NDM / 64), 256, 0, stream>>>(w_out, woT, NDM, NDM);

    // 1) qkv projection, epilogue splits into per-head q/k + transposed v
    gemm128<1><<<dim3(3 * NDM / 128, NM / 128), 256, 0, stream>>>(
        xb, wqT, b_qkv, nullptr, qH, kH, vT, NM, 3 * NDM, NDM);

    // 2) causal MFMA flash attention
    attn_mfma<<<dim3((NS / 64) * NB * NH), 256, 0, stream>>>(qH, kH, vT, atto);

    // 3) output projection (fp32 out)
    gemm128<0><<<dim3(NDM / 128, NM / 128), 256, 0, stream>>>(
        atto, woT, b_out, out, nullptr, nullptr, nullptr, NM, NDM, NDM);
}